// Round 6
// baseline (160.373 us; speedup 1.0000x reference)
//
#include <hip/hip_runtime.h>
#include <hip/hip_bf16.h>

#define DOUT 128
#define NEG 0.01f

__device__ __forceinline__ float bf2f(unsigned short u) {
    union { unsigned int i; float f; } c; c.i = ((unsigned int)u) << 16; return c.f;
}
__device__ __forceinline__ unsigned short f2bf(float f) {
    union { float f; unsigned int i; } c; c.f = f;
    unsigned int r = c.i + 0x7FFF + ((c.i >> 16) & 1);   // round-to-nearest-even
    return (unsigned short)(r >> 16);
}

// ---------------- fused: GEMM h = x@W+b (+ s_dst/s_src) | CSR offsets ----------------
// Blocks [0, gemmBlocks) do the GEMM; blocks beyond build CSR offsets from the
// sorted edge_dst. Independent work made concurrent in one dispatch.
// NO unroll pragma / manual prefetch on the k-loop: full unroll spilled to
// scratch at VGPR=256 (R3 post-mortem: 600us, 1.5GB scratch traffic).
#define BM 64

__global__ __launch_bounds__(256)
void gemm_build(const float* __restrict__ x, const float* __restrict__ W,
                const float* __restrict__ b, const float* __restrict__ a_w,
                unsigned short* __restrict__ h, float* __restrict__ s_dst,
                float* __restrict__ s_src,
                const int* __restrict__ edge_dst, int* __restrict__ offsets,
                int N, int E, int gemmBlocks)
{
    const int tid = threadIdx.x;

    if (blockIdx.x >= gemmBlocks) {
        // ---- CSR offsets section ----
        int e = (blockIdx.x - gemmBlocks) * 256 + tid;
        if (e < E) {
            int d = edge_dst[e];
            int prev = (e == 0) ? -1 : edge_dst[e - 1];
            for (int n = prev + 1; n <= d; ++n) offsets[n] = e;
            if (e == E - 1)
                for (int n = d + 1; n <= N; ++n) offsets[n] = E;
        }
        return;
    }

    // ---- GEMM section ----
    __shared__ float Xs[BM][DOUT];   // 32 KB
    const int row0 = blockIdx.x * BM;

    // stage x tile: 64x128 floats = 2048 float4, 8 per thread, coalesced
#pragma unroll
    for (int i = 0; i < 8; ++i) {
        int q = i * 256 + tid;
        int r = q >> 5;
        int c = (q & 31) << 2;
        int gn = row0 + r;
        float4 v = make_float4(0.f, 0.f, 0.f, 0.f);
        if (gn < N) v = *(const float4*)&x[(size_t)gn * DOUT + c];
        *(float4*)&Xs[r][c] = v;
    }
    __syncthreads();

    const int dg = (tid & 31) << 2;     // dim base (4 dims)
    const int r0 = (tid >> 5) << 3;     // node base (8 nodes)

    float acc[8][4];
#pragma unroll
    for (int i = 0; i < 8; ++i)
#pragma unroll
        for (int j = 0; j < 4; ++j) acc[i][j] = 0.f;

    for (int k = 0; k < DOUT; k += 4) {
        float4 w0 = *(const float4*)&W[(size_t)(k + 0) * DOUT + dg];
        float4 w1 = *(const float4*)&W[(size_t)(k + 1) * DOUT + dg];
        float4 w2 = *(const float4*)&W[(size_t)(k + 2) * DOUT + dg];
        float4 w3 = *(const float4*)&W[(size_t)(k + 3) * DOUT + dg];
#pragma unroll
        for (int i = 0; i < 8; ++i) {
            float4 xq = *(float4*)&Xs[r0 + i][k];   // wave-broadcast (free)
            acc[i][0] += xq.x * w0.x + xq.y * w1.x + xq.z * w2.x + xq.w * w3.x;
            acc[i][1] += xq.x * w0.y + xq.y * w1.y + xq.z * w2.y + xq.w * w3.y;
            acc[i][2] += xq.x * w0.z + xq.y * w1.z + xq.z * w2.z + xq.w * w3.z;
            acc[i][3] += xq.x * w0.w + xq.y * w1.w + xq.z * w2.w + xq.w * w3.w;
        }
    }

    const float4 bb   = *(const float4*)&b[dg];
    const float4 aw_d = *(const float4*)&a_w[dg];
    const float4 aw_s = *(const float4*)&a_w[DOUT + dg];
#pragma unroll
    for (int i = 0; i < 8; ++i) {
        int gn = row0 + r0 + i;
        float4 o;
        o.x = acc[i][0] + bb.x;
        o.y = acc[i][1] + bb.y;
        o.z = acc[i][2] + bb.z;
        o.w = acc[i][3] + bb.w;
        if (gn < N) {
            ushort4 hb;
            hb.x = f2bf(o.x); hb.y = f2bf(o.y); hb.z = f2bf(o.z); hb.w = f2bf(o.w);
            *(ushort4*)&h[(size_t)gn * DOUT + dg] = hb;
        }
        float sd = o.x * aw_d.x + o.y * aw_d.y + o.z * aw_d.z + o.w * aw_d.w;
        float ss = o.x * aw_s.x + o.y * aw_s.y + o.z * aw_s.z + o.w * aw_s.w;
#pragma unroll
        for (int off = 16; off; off >>= 1) {
            sd += __shfl_xor(sd, off, 32);
            ss += __shfl_xor(ss, off, 32);
        }
        if ((tid & 31) == 0 && gn < N) { s_dst[gn] = sd; s_src[gn] = ss; }
    }
}

// ---------------- segment softmax + weighted aggregation (wave per node) ----------------
// pass 3: half-wave (32 lanes) per edge row, bf16x4 (8B) loads, 16 edges/round
// (8 loads per lane in flight against L2-miss latency).
#define WBUF 256

__global__ __launch_bounds__(256)
void gat_agg(const int* __restrict__ edge_src, const int* __restrict__ offsets,
             const unsigned short* __restrict__ h, const float* __restrict__ s_src,
             const float* __restrict__ s_dst, const float* __restrict__ a_b,
             float* __restrict__ out, int N)
{
    __shared__ float eb_all[4][WBUF];
    __shared__ int   sb_all[4][WBUF];
    const int lane = threadIdx.x & 63;
    const int wv = threadIdx.x >> 6;
    const int n = blockIdx.x * 4 + wv;
    const bool active = (n < N);

    float* eb = eb_all[wv];
    int*   sb = sb_all[wv];

    int start = 0, end = 0;
    float sdn = 0.f;
    if (active) {
        start = offsets[n];
        end = offsets[n + 1];
        sdn = s_dst[n] + a_b[0];
    }
    const int deg = end - start;
    const int cached = deg < WBUF ? deg : WBUF;

    // ---- pass 1: logits (registers) + src cache (LDS) + wave max ----
    float lgr[4];
    float mymax = -3.4e38f;
#pragma unroll
    for (int t = 0; t < 4; ++t) {
        int i = lane + t * 64;
        if (i < cached) {
            int s = edge_src[start + i];
            float lg = sdn + s_src[s];
            lg = lg >= 0.f ? lg : NEG * lg;
            sb[i] = s;
            lgr[t] = lg;
            mymax = fmaxf(mymax, lg);
        }
    }
    for (int i = WBUF + lane; i < deg; i += 64) {     // overflow path
        float lg = sdn + s_src[edge_src[start + i]];
        lg = lg >= 0.f ? lg : NEG * lg;
        mymax = fmaxf(mymax, lg);
    }
#pragma unroll
    for (int o = 32; o; o >>= 1) mymax = fmaxf(mymax, __shfl_xor(mymax, o, 64));

    // ---- pass 2: exp -> LDS, wave sum ----
    float mysum = 0.f;
#pragma unroll
    for (int t = 0; t < 4; ++t) {
        int i = lane + t * 64;
        if (i < cached) {
            float ex = __expf(lgr[t] - mymax);
            eb[i] = ex;
            mysum += ex;
        }
    }
    for (int i = WBUF + lane; i < deg; i += 64) {     // overflow path
        float lg = sdn + s_src[edge_src[start + i]];
        lg = lg >= 0.f ? lg : NEG * lg;
        mysum += __expf(lg - mymax);
    }
#pragma unroll
    for (int o = 32; o; o >>= 1) mysum += __shfl_xor(mysum, o, 64);

    __syncthreads();   // eb/sb visible across lanes

    // ---- pass 3: half-wave per edge, bf16x4 loads, 16 edges per round ----
    const ushort4* __restrict__ h4 = (const ushort4*)h;   // row stride = 32
    const int half = lane >> 5;       // 0 or 1
    const int sub  = lane & 31;       // dims [sub*4, sub*4+4)
    float4 acc = make_float4(0.f, 0.f, 0.f, 0.f);

    int e = 0;
    for (; e + 16 <= cached; e += 16) {
        int     si[8];
        float   wi[8];
        ushort4 vi[8];
#pragma unroll
        for (int t = 0; t < 8; ++t) {
            int i = e + 2 * t + half;
            si[t] = sb[i];
            wi[t] = eb[i];
        }
#pragma unroll
        for (int t = 0; t < 8; ++t) vi[t] = h4[(size_t)si[t] * 32 + sub];
#pragma unroll
        for (int t = 0; t < 8; ++t) {
            acc.x += wi[t] * bf2f(vi[t].x); acc.y += wi[t] * bf2f(vi[t].y);
            acc.z += wi[t] * bf2f(vi[t].z); acc.w += wi[t] * bf2f(vi[t].w);
        }
    }
    for (; e < cached; e += 2) {
        int i = e + half;
        if (i < cached) {
            int s = sb[i];
            float w = eb[i];
            ushort4 v = h4[(size_t)s * 32 + sub];
            acc.x += w * bf2f(v.x); acc.y += w * bf2f(v.y);
            acc.z += w * bf2f(v.z); acc.w += w * bf2f(v.w);
        }
    }
    for (int i = cached; i < deg; ++i) {              // overflow path (half 0 only)
        if (half == 0) {
            int s = edge_src[start + i];
            float lg = sdn + s_src[s];
            lg = lg >= 0.f ? lg : NEG * lg;
            float w = __expf(lg - mymax);
            ushort4 v = h4[(size_t)s * 32 + sub];
            acc.x += w * bf2f(v.x); acc.y += w * bf2f(v.y);
            acc.z += w * bf2f(v.z); acc.w += w * bf2f(v.w);
        }
    }

    // combine the two half-wave partials
    acc.x += __shfl_xor(acc.x, 32, 64);
    acc.y += __shfl_xor(acc.y, 32, 64);
    acc.z += __shfl_xor(acc.z, 32, 64);
    acc.w += __shfl_xor(acc.w, 32, 64);

    if (active && half == 0) {
        const float inv = 1.f / fmaxf(mysum, 1e-16f);
        float4 o;
        o.x = acc.x * inv; o.y = acc.y * inv; o.z = acc.z * inv; o.w = acc.w * inv;
        ((float4*)out)[(size_t)n * 32 + sub] = o;
    }
}

extern "C" void kernel_launch(void* const* d_in, const int* in_sizes, int n_in,
                              void* d_out, int out_size, void* d_ws, size_t ws_size,
                              hipStream_t stream)
{
    const float* x        = (const float*)d_in[0];
    const int*   edge_src = (const int*)d_in[1];
    const int*   edge_dst = (const int*)d_in[2];
    const float* W        = (const float*)d_in[3];
    const float* b        = (const float*)d_in[4];
    const float* a_w      = (const float*)d_in[5];
    const float* a_b      = (const float*)d_in[6];
    const int N = in_sizes[0] / DOUT;
    const int E = in_sizes[1];
    float* out = (float*)d_out;

    char* ws = (char*)d_ws;
    unsigned short* h = (unsigned short*)ws;  ws += (size_t)N * DOUT * sizeof(unsigned short);
    float* s_dst   = (float*)ws;  ws += (size_t)N * sizeof(float);
    float* s_src   = (float*)ws;  ws += (size_t)N * sizeof(float);
    int*   offsets = (int*)ws;    ws += (size_t)(N + 1) * sizeof(int);

    const int gemmBlocks = (N + BM - 1) / BM;
    const int buildBlocks = (E + 255) / 256;
    gemm_build<<<gemmBlocks + buildBlocks, 256, 0, stream>>>(
        x, W, b, a_w, h, s_dst, s_src, edge_dst, offsets, N, E, gemmBlocks);
    gat_agg<<<(N + 3) / 4, 256, 0, stream>>>(edge_src, offsets, h, s_src, s_dst, a_b, out, N);
}

// Round 7
// 152.468 us; speedup vs baseline: 1.0518x; 1.0518x over previous
//
#include <hip/hip_runtime.h>
#include <hip/hip_bf16.h>

#define DOUT 128
#define NEG 0.01f

__device__ __forceinline__ float bf2f(unsigned short u) {
    union { unsigned int i; float f; } c; c.i = ((unsigned int)u) << 16; return c.f;
}
__device__ __forceinline__ unsigned short f2bf(float f) {
    union { float f; unsigned int i; } c; c.f = f;
    unsigned int r = c.i + 0x7FFF + ((c.i >> 16) & 1);   // round-to-nearest-even
    return (unsigned short)(r >> 16);
}

// ---------------- fused: GEMM h = x@W+b (+ s_dst/s_src) | CSR offsets ----------------
// NO unroll pragma / manual prefetch on the k-loop: full unroll spilled to
// scratch at VGPR=256 (R3 post-mortem: 600us, 1.5GB scratch traffic).
#define BM 64

__global__ __launch_bounds__(256)
void gemm_build(const float* __restrict__ x, const float* __restrict__ W,
                const float* __restrict__ b, const float* __restrict__ a_w,
                unsigned short* __restrict__ h, float* __restrict__ s_dst,
                float* __restrict__ s_src,
                const int* __restrict__ edge_dst, int* __restrict__ offsets,
                int N, int E, int gemmBlocks)
{
    const int tid = threadIdx.x;

    if (blockIdx.x >= gemmBlocks) {
        // ---- CSR offsets section ----
        int e = (blockIdx.x - gemmBlocks) * 256 + tid;
        if (e < E) {
            int d = edge_dst[e];
            int prev = (e == 0) ? -1 : edge_dst[e - 1];
            for (int n = prev + 1; n <= d; ++n) offsets[n] = e;
            if (e == E - 1)
                for (int n = d + 1; n <= N; ++n) offsets[n] = E;
        }
        return;
    }

    // ---- GEMM section ----
    __shared__ float Xs[BM][DOUT];   // 32 KB
    const int row0 = blockIdx.x * BM;

#pragma unroll
    for (int i = 0; i < 8; ++i) {
        int q = i * 256 + tid;
        int r = q >> 5;
        int c = (q & 31) << 2;
        int gn = row0 + r;
        float4 v = make_float4(0.f, 0.f, 0.f, 0.f);
        if (gn < N) v = *(const float4*)&x[(size_t)gn * DOUT + c];
        *(float4*)&Xs[r][c] = v;
    }
    __syncthreads();

    const int dg = (tid & 31) << 2;     // dim base (4 dims)
    const int r0 = (tid >> 5) << 3;     // node base (8 nodes)

    float acc[8][4];
#pragma unroll
    for (int i = 0; i < 8; ++i)
#pragma unroll
        for (int j = 0; j < 4; ++j) acc[i][j] = 0.f;

    for (int k = 0; k < DOUT; k += 4) {
        float4 w0 = *(const float4*)&W[(size_t)(k + 0) * DOUT + dg];
        float4 w1 = *(const float4*)&W[(size_t)(k + 1) * DOUT + dg];
        float4 w2 = *(const float4*)&W[(size_t)(k + 2) * DOUT + dg];
        float4 w3 = *(const float4*)&W[(size_t)(k + 3) * DOUT + dg];
#pragma unroll
        for (int i = 0; i < 8; ++i) {
            float4 xq = *(float4*)&Xs[r0 + i][k];   // wave-broadcast (free)
            acc[i][0] += xq.x * w0.x + xq.y * w1.x + xq.z * w2.x + xq.w * w3.x;
            acc[i][1] += xq.x * w0.y + xq.y * w1.y + xq.z * w2.y + xq.w * w3.y;
            acc[i][2] += xq.x * w0.z + xq.y * w1.z + xq.z * w2.z + xq.w * w3.z;
            acc[i][3] += xq.x * w0.w + xq.y * w1.w + xq.z * w2.w + xq.w * w3.w;
        }
    }

    const float4 bb   = *(const float4*)&b[dg];
    const float4 aw_d = *(const float4*)&a_w[dg];
    const float4 aw_s = *(const float4*)&a_w[DOUT + dg];
#pragma unroll
    for (int i = 0; i < 8; ++i) {
        int gn = row0 + r0 + i;
        float4 o;
        o.x = acc[i][0] + bb.x;
        o.y = acc[i][1] + bb.y;
        o.z = acc[i][2] + bb.z;
        o.w = acc[i][3] + bb.w;
        if (gn < N) {
            ushort4 hb;
            hb.x = f2bf(o.x); hb.y = f2bf(o.y); hb.z = f2bf(o.z); hb.w = f2bf(o.w);
            *(ushort4*)&h[(size_t)gn * DOUT + dg] = hb;
        }
        float sd = o.x * aw_d.x + o.y * aw_d.y + o.z * aw_d.z + o.w * aw_d.w;
        float ss = o.x * aw_s.x + o.y * aw_s.y + o.z * aw_s.z + o.w * aw_s.w;
#pragma unroll
        for (int off = 16; off; off >>= 1) {
            sd += __shfl_xor(sd, off, 32);
            ss += __shfl_xor(ss, off, 32);
        }
        if ((tid & 31) == 0 && gn < N) { s_dst[gn] = sd; s_src[gn] = ss; }
    }
}

// ---------------- segment softmax + aggregation: 16-lane group per node ----------------
// avg degree = E/N = 16, so a 16-lane group maps lanes 1:1 to edges (vs 75%
// idle lanes in the old wave-per-node layout). Weights/src indices live in
// registers (4 slots = up to 64 edges; overflow recomputes), broadcast with
// width-16 shuffles. Pass 3 loads a full 256B bf16 row as 16 x uint4,
// 4 rows in flight. No LDS, no barriers (groups are within one wave).
#define GL 16      // lanes per group
#define KSLOT 4    // register slots -> 64 edges cached

__device__ __forceinline__ void fma8(unsigned int u0, unsigned int u1,
                                     unsigned int u2, unsigned int u3,
                                     float w, float* a) {
    union { unsigned int i; float f; } c;
    c.i = u0 << 16;        a[0] += w * c.f;
    c.i = u0 & 0xFFFF0000u; a[1] += w * c.f;
    c.i = u1 << 16;        a[2] += w * c.f;
    c.i = u1 & 0xFFFF0000u; a[3] += w * c.f;
    c.i = u2 << 16;        a[4] += w * c.f;
    c.i = u2 & 0xFFFF0000u; a[5] += w * c.f;
    c.i = u3 << 16;        a[6] += w * c.f;
    c.i = u3 & 0xFFFF0000u; a[7] += w * c.f;
}

__global__ __launch_bounds__(256)
void gat_agg(const int* __restrict__ edge_src, const int* __restrict__ offsets,
             const unsigned short* __restrict__ h, const float* __restrict__ s_src,
             const float* __restrict__ s_dst, const float* __restrict__ a_b,
             float* __restrict__ out, int N)
{
    const int lg16 = threadIdx.x & (GL - 1);           // lane within group
    const int n = blockIdx.x * 16 + (threadIdx.x >> 4); // node for this group
    const bool active = (n < N);

    int start = 0, end = 0;
    float sdn = 0.f;
    if (active) {
        start = offsets[n];
        end = offsets[n + 1];
        sdn = s_dst[n] + a_b[0];
    }
    const int deg = end - start;

    // ---- pass 1: logits into register slots + group max ----
    float lgr[KSLOT];
    int   sreg[KSLOT];
    float mymax = -3.4e38f;
#pragma unroll
    for (int t = 0; t < KSLOT; ++t) {
        int i = lg16 + t * GL;
        lgr[t] = -3.4e38f; sreg[t] = 0;
        if (i < deg) {
            int s = edge_src[start + i];
            float lg = sdn + s_src[s];
            lg = lg >= 0.f ? lg : NEG * lg;
            sreg[t] = s; lgr[t] = lg;
            mymax = fmaxf(mymax, lg);
        }
    }
    for (int i = lg16 + KSLOT * GL; i < deg; i += GL) {  // overflow (deg>64, ~never)
        float lg = sdn + s_src[edge_src[start + i]];
        lg = lg >= 0.f ? lg : NEG * lg;
        mymax = fmaxf(mymax, lg);
    }
#pragma unroll
    for (int o = 8; o; o >>= 1) mymax = fmaxf(mymax, __shfl_xor(mymax, o, GL));

    // ---- pass 2: exp in registers + group sum ----
    float wr[KSLOT];
    float mysum = 0.f;
#pragma unroll
    for (int t = 0; t < KSLOT; ++t) {
        float ex = 0.f;
        if (lg16 + t * GL < deg) ex = __expf(lgr[t] - mymax);
        wr[t] = ex;
        mysum += ex;
    }
    for (int i = lg16 + KSLOT * GL; i < deg; i += GL) {  // overflow
        float lg = sdn + s_src[edge_src[start + i]];
        lg = lg >= 0.f ? lg : NEG * lg;
        mysum += __expf(lg - mymax);
    }
#pragma unroll
    for (int o = 8; o; o >>= 1) mysum += __shfl_xor(mysum, o, GL);

    // ---- pass 3: gather rows; group lane = 8 dims (16 lanes x 16B = 256B row) ----
    const uint4* __restrict__ h4 = (const uint4*)h;      // row stride = 16 uint4
    float a[8];
#pragma unroll
    for (int q = 0; q < 8; ++q) a[q] = 0.f;

    const int degc = deg < KSLOT * GL ? deg : KSLOT * GL;
#pragma unroll
    for (int t = 0; t < KSLOT; ++t) {
        const int base = t * GL;
        if (base >= degc) break;
        const int cnt = (degc - base) < GL ? (degc - base) : GL;
        const float wt = wr[t];
        const int   st = sreg[t];
        int j = 0;
        for (; j + 4 <= cnt; j += 4) {
            float w0 = __shfl(wt, j + 0, GL); int s0 = __shfl(st, j + 0, GL);
            float w1 = __shfl(wt, j + 1, GL); int s1 = __shfl(st, j + 1, GL);
            float w2 = __shfl(wt, j + 2, GL); int s2 = __shfl(st, j + 2, GL);
            float w3 = __shfl(wt, j + 3, GL); int s3 = __shfl(st, j + 3, GL);
            uint4 v0 = h4[(size_t)s0 * 16 + lg16];
            uint4 v1 = h4[(size_t)s1 * 16 + lg16];
            uint4 v2 = h4[(size_t)s2 * 16 + lg16];
            uint4 v3 = h4[(size_t)s3 * 16 + lg16];
            fma8(v0.x, v0.y, v0.z, v0.w, w0, a);
            fma8(v1.x, v1.y, v1.z, v1.w, w1, a);
            fma8(v2.x, v2.y, v2.z, v2.w, w2, a);
            fma8(v3.x, v3.y, v3.z, v3.w, w3, a);
        }
        for (; j < cnt; ++j) {
            float w = __shfl(wt, j, GL); int s = __shfl(st, j, GL);
            uint4 v = h4[(size_t)s * 16 + lg16];
            fma8(v.x, v.y, v.z, v.w, w, a);
        }
    }
    for (int i = KSLOT * GL; i < deg; ++i) {             // overflow (uniform addr)
        int s = edge_src[start + i];
        float lgv = sdn + s_src[s];
        lgv = lgv >= 0.f ? lgv : NEG * lgv;
        float w = __expf(lgv - mymax);
        uint4 v = h4[(size_t)s * 16 + lg16];
        fma8(v.x, v.y, v.z, v.w, w, a);
    }

    if (active) {
        const float inv = 1.f / fmaxf(mysum, 1e-16f);
        float4 o0, o1;
        o0.x = a[0] * inv; o0.y = a[1] * inv; o0.z = a[2] * inv; o0.w = a[3] * inv;
        o1.x = a[4] * inv; o1.y = a[5] * inv; o1.z = a[6] * inv; o1.w = a[7] * inv;
        float4* op = (float4*)&out[(size_t)n * DOUT + lg16 * 8];
        op[0] = o0;
        op[1] = o1;
    }
}

extern "C" void kernel_launch(void* const* d_in, const int* in_sizes, int n_in,
                              void* d_out, int out_size, void* d_ws, size_t ws_size,
                              hipStream_t stream)
{
    const float* x        = (const float*)d_in[0];
    const int*   edge_src = (const int*)d_in[1];
    const int*   edge_dst = (const int*)d_in[2];
    const float* W        = (const float*)d_in[3];
    const float* b        = (const float*)d_in[4];
    const float* a_w      = (const float*)d_in[5];
    const float* a_b      = (const float*)d_in[6];
    const int N = in_sizes[0] / DOUT;
    const int E = in_sizes[1];
    float* out = (float*)d_out;

    char* ws = (char*)d_ws;
    unsigned short* h = (unsigned short*)ws;  ws += (size_t)N * DOUT * sizeof(unsigned short);
    float* s_dst   = (float*)ws;  ws += (size_t)N * sizeof(float);
    float* s_src   = (float*)ws;  ws += (size_t)N * sizeof(float);
    int*   offsets = (int*)ws;    ws += (size_t)(N + 1) * sizeof(int);

    const int gemmBlocks = (N + BM - 1) / BM;
    const int buildBlocks = (E + 255) / 256;
    gemm_build<<<gemmBlocks + buildBlocks, 256, 0, stream>>>(
        x, W, b, a_w, h, s_dst, s_src, edge_dst, offsets, N, E, gemmBlocks);
    gat_agg<<<(N + 15) / 16, 256, 0, stream>>>(edge_src, offsets, h, s_src, s_dst, a_b, out, N);
}